// Round 16
// baseline (118.732 us; speedup 1.0000x reference)
//
#include <hip/hip_runtime.h>
#include <hip/hip_bf16.h>

#define S_LEN 2048
#define E_DIM 1024
#define NH 16
#define HD 64
#define ATTN_SCALE 0.03125f                 // 1/sqrt(1024)
#define QSCALE_L2E 0.045084312f             // ATTN_SCALE * log2(e): exp2-domain softmax

typedef __attribute__((ext_vector_type(8))) short short8;
typedef __attribute__((ext_vector_type(8))) unsigned short ushort8;
typedef __attribute__((ext_vector_type(4))) unsigned short ushort4_t;
typedef __attribute__((ext_vector_type(4))) float f32x4;
typedef __attribute__((ext_vector_type(4))) float f4;
typedef __attribute__((ext_vector_type(2))) unsigned int uint2_t;

__device__ __forceinline__ float bf2f(unsigned short u) {
    unsigned int x = ((unsigned int)u) << 16;
    return __builtin_bit_cast(float, x);
}
__device__ __forceinline__ unsigned short f2bf(float f) {
    unsigned int x = __builtin_bit_cast(unsigned int, f);
    x += 0x7FFFu + ((x >> 16) & 1u);   // RNE
    return (unsigned short)(x >> 16);
}
__device__ __forceinline__ float exp2_fast(float x) {   // 2^x, one v_exp_f32
    float r;
    asm("v_exp_f32 %0, %1" : "=v"(r) : "v"(x));
    return r;
}
__device__ __forceinline__ void gload16(const unsigned short* g, unsigned short* l) {
    __builtin_amdgcn_global_load_lds(
        (__attribute__((address_space(1))) void*)g,
        (__attribute__((address_space(3))) void*)l, 16, 0, 0);
}

// ---------------- merged prep: x->bf16 | rope table | W transpose ----------------
__global__ __launch_bounds__(256) void k_prep(const float* __restrict__ x,
                                              unsigned short* __restrict__ xb,
                                              const float* W0, const float* W1,
                                              const float* W2, const float* W3,
                                              unsigned short* Tqkv,
                                              unsigned short* Twout,
                                              float* __restrict__ cosT,
                                              float* __restrict__ sinT) {
    int bid = blockIdx.x;
    int tid = threadIdx.x;
    if (bid < 2048) {
        size_t i = ((size_t)bid * 256 + tid) * 8;
        f4 a = *(const f4*)(x + i);
        f4 b = *(const f4*)(x + i + 4);
        ushort8 o;
        o[0] = f2bf(a[0]); o[1] = f2bf(a[1]); o[2] = f2bf(a[2]); o[3] = f2bf(a[3]);
        o[4] = f2bf(b[0]); o[5] = f2bf(b[1]); o[6] = f2bf(b[2]); o[7] = f2bf(b[3]);
        *(ushort8*)(xb + i) = o;
    } else if (bid < 2304) {
        int idx = (bid - 2048) * 256 + tid;
        int s = idx >> 5, j = idx & 31;
        float inv = expf(-(float)j * (9.210340371976184f / 32.f));
        float ang = (float)s * inv;
        cosT[idx] = cosf(ang);
        sinT[idx] = sinf(ang);
    } else {
        int t = bid - 2304;                  // 0..4095
        int bx = (t & 31) * 32, by = ((t >> 5) & 31) * 32, z = t >> 10;
        const float* W; unsigned short* T;
        switch (z) {
            case 0: W = W0; T = Tqkv; break;
            case 1: W = W1; T = Tqkv + 1048576; break;
            case 2: W = W2; T = Tqkv + 2097152; break;
            default: W = W3; T = Twout; break;
        }
        __shared__ float tile[32][33];
        int tx = tid & 31, ty = tid >> 5;    // 32 x 8
#pragma unroll
        for (int i = 0; i < 4; i++)
            tile[ty + i * 8][tx] = W[(size_t)(by + ty + i * 8) * E_DIM + bx + tx];
        __syncthreads();
#pragma unroll
        for (int i = 0; i < 4; i++)
            T[(size_t)(bx + ty + i * 8) * E_DIM + by + tx] = f2bf(tile[tx][ty + i * 8]);
    }
}

// ---------------- QKV GEMM, m97 structure; epilogue: RoPE Q/K + VP16 pack -------
// VP16: per (bh, kt32, nf): 64 lanes x 8 contiguous bf16 MFMA B-frag:
//   off = ((bh*64+kt)*4+nf)*512 + lane*8 + j ; lane=(d&15)|(((s&31)>>3)<<4), j=s&7
__global__ __launch_bounds__(256, 3)
void k_gemm97(const unsigned short* __restrict__ A,
              const unsigned short* __restrict__ B,
              unsigned short* __restrict__ Qo,
              unsigned short* __restrict__ Ko,
              unsigned short* __restrict__ VPo,
              const float* __restrict__ cosT,
              const float* __restrict__ sinT) {
    constexpr int NBN = 24;
    constexpr int NWG = 32 * NBN;            // 768
    __shared__ unsigned short Alds[4096];    // [128][32] linear
    __shared__ unsigned short Blds[4096];
    int tid = threadIdx.x, lane = tid & 63, wid = tid >> 6;
    int l15 = lane & 15, lg = lane >> 4;
    int wr = wid >> 1, wc = wid & 1;
    int orig = blockIdx.y * NBN + blockIdx.x;
    int wg = (orig & 7) * (NWG / 8) + (orig >> 3);
    int bm = wg / NBN, bn = wg % NBN;
    int c0 = wid * 2, c1c = wid * 2 + 1;
    int srow0 = c0 * 16 + (lane >> 2);
    int srow1 = c1c * 16 + (lane >> 2);
    int scol = (lane & 3) * 8;
    const unsigned short* As0 = A + (size_t)(bm * 128 + srow0) * E_DIM + scol;
    const unsigned short* As1 = A + (size_t)(bm * 128 + srow1) * E_DIM + scol;
    const unsigned short* Bs0 = B + (size_t)(bn * 128 + srow0) * E_DIM + scol;
    const unsigned short* Bs1 = B + (size_t)(bn * 128 + srow1) * E_DIM + scol;
    unsigned short* Ad0 = Alds + c0 * 512;
    unsigned short* Ad1 = Alds + c1c * 512;
    unsigned short* Bd0 = Blds + c0 * 512;
    unsigned short* Bd1 = Blds + c1c * 512;
    f32x4 acc[4][4] = {};
    for (int k0 = 0; k0 < E_DIM; k0 += 32) {
        gload16(As0 + k0, Ad0);
        gload16(As1 + k0, Ad1);
        gload16(Bs0 + k0, Bd0);
        gload16(Bs1 + k0, Bd1);
        __syncthreads();
        short8 af[4], bfr[4];
#pragma unroll
        for (int mf = 0; mf < 4; mf++)
            af[mf] = *(const short8*)(Alds + (wr * 64 + mf * 16 + l15) * 32 + lg * 8);
#pragma unroll
        for (int nf = 0; nf < 4; nf++)
            bfr[nf] = *(const short8*)(Blds + (wc * 64 + nf * 16 + l15) * 32 + lg * 8);
#pragma unroll
        for (int mf = 0; mf < 4; mf++)
#pragma unroll
            for (int nf = 0; nf < 4; nf++)
                acc[mf][nf] = __builtin_amdgcn_mfma_f32_16x16x32_bf16(
                    af[mf], bfr[nf], acc[mf][nf], 0, 0, 0);
        __syncthreads();
    }
#pragma unroll
    for (int mf = 0; mf < 4; mf++) {
        int r0 = bm * 128 + wr * 64 + mf * 16 + lg * 4;
#pragma unroll
        for (int nf = 0; nf < 4; nf++) {
            int colg = bn * 128 + wc * 64 + nf * 16 + l15;
            int z = colg >> 10, c1 = colg & 1023;
            if (z == 2) {
                int h = c1 >> 6, d = c1 & 63;
                int bb = r0 >> 11, s = r0 & 2047;
                int bh2 = bb * 16 + h;
                int kt = s >> 5;
                int nfv = d >> 4;
                int lanev = (d & 15) | (((s & 31) >> 3) << 4);
                size_t off = ((size_t)((bh2 * 64 + kt) * 4 + nfv)) * 512 +
                             (size_t)lanev * 8 + (s & 7);
                ushort4_t p;
#pragma unroll
                for (int r = 0; r < 4; r++) p[r] = f2bf(acc[mf][nf][r]);
                *(ushort4_t*)(VPo + off) = p;
            } else {
                unsigned short* T = z ? Ko : Qo;
                int dl = c1 & 63, j = dl >> 1;
                float sgn = (dl & 1) ? 1.f : -1.f;
                float scq = z ? 1.f : QSCALE_L2E;
#pragma unroll
                for (int r = 0; r < 4; r++) {
                    int row = r0 + r, s = row & 2047;
                    float c = cosT[s * 32 + j], sn = sinT[s * 32 + j];
                    float v = acc[mf][nf][r];
                    float p = __shfl_xor(v, 1);
                    T[(size_t)row * E_DIM + c1] = f2bf((v * c + sgn * p * sn) * scq);
                }
            }
        }
    }
}

// ---------------- out-proj GEMM (unchanged R15) ----------------
template <int BM, int BN, int NBN>
__global__ __launch_bounds__(256, 3)
void k_gemmo(const unsigned short* __restrict__ A,
             const unsigned short* __restrict__ B,
             float* __restrict__ Fo) {
    constexpr int THREADS = 256;
    constexpr int WM = BM / 2, WN = BN / 2;
    constexpr int FM = WM / 16, FN = WN / 16;
    constexpr int NT = E_DIM / 64;
    constexpr int AR = BM * 8 / THREADS;
    constexpr int BR = BN * 8 / THREADS;
    constexpr int STG = AR + BR;
    constexpr int NWG = (4096 / BM) * NBN;
    __shared__ unsigned short Al[2][BM * 64];
    __shared__ unsigned short Bl[2][BN * 64];
    int tid = threadIdx.x, lane = tid & 63, wid = tid >> 6;
    int l15 = lane & 15, lg = lane >> 4;
    int wr = wid >> 1, wc = wid & 1;
    int orig = blockIdx.y * NBN + blockIdx.x;
    int wg = (orig & 7) * (NWG / 8) + (orig >> 3);
    int bm = wg / NBN, bn = wg % NBN;

    auto stage = [&](int buf, int k0) {
#pragma unroll
        for (int i = 0; i < AR; i++) {
            int r = i * (THREADS / 8) + wid * 8 + (lane >> 3);
            int cs = (lane & 7) ^ (r & 7);
            gload16(A + (size_t)(bm * BM + r) * E_DIM + k0 + cs * 8,
                    &Al[buf][i * (THREADS * 8) + wid * 512]);
        }
#pragma unroll
        for (int i = 0; i < BR; i++) {
            int r = i * (THREADS / 8) + wid * 8 + (lane >> 3);
            int cs = (lane & 7) ^ (r & 7);
            gload16(B + (size_t)(bn * BN + r) * E_DIM + k0 + cs * 8,
                    &Bl[buf][i * (THREADS * 8) + wid * 512]);
        }
    };

    f32x4 acc[FM][FN] = {};
    stage(0, 0);
    for (int t = 0; t < NT; t++) {
        int cur = t & 1;
        if (t + 1 < NT) {
            stage(cur ^ 1, (t + 1) * 64);
            asm volatile("s_waitcnt vmcnt(%0)" :: "n"(STG) : "memory");
        } else {
            asm volatile("s_waitcnt vmcnt(0)" ::: "memory");
        }
        __builtin_amdgcn_s_barrier();
        __builtin_amdgcn_sched_barrier(0);
#pragma unroll
        for (int ks = 0; ks < 2; ks++) {
            short8 af[FM], bfv[FN];
#pragma unroll
            for (int m = 0; m < FM; m++) {
                int r = wr * WM + m * 16 + l15;
                int gc = ks * 4 + lg;
                af[m] = *(const short8*)&Al[cur][r * 64 + ((gc ^ (r & 7)) << 3)];
            }
#pragma unroll
            for (int n = 0; n < FN; n++) {
                int r = wc * WN + n * 16 + l15;
                int gc = ks * 4 + lg;
                bfv[n] = *(const short8*)&Bl[cur][r * 64 + ((gc ^ (r & 7)) << 3)];
            }
            __builtin_amdgcn_s_setprio(1);
#pragma unroll
            for (int m = 0; m < FM; m++)
#pragma unroll
                for (int n = 0; n < FN; n++)
                    acc[m][n] = __builtin_amdgcn_mfma_f32_16x16x32_bf16(
                        af[m], bfv[n], acc[m][n], 0, 0, 0);
            __builtin_amdgcn_s_setprio(0);
        }
        __builtin_amdgcn_s_barrier();
    }
#pragma unroll
    for (int m = 0; m < FM; m++) {
        int r0 = bm * BM + wr * WM + m * 16 + lg * 4;
#pragma unroll
        for (int n = 0; n < FN; n++) {
            int colg = bn * BN + wc * WN + n * 16 + l15;
#pragma unroll
            for (int r = 0; r < 4; r++)
                Fo[(size_t)(r0 + r) * E_DIM + colg] = acc[m][n][r];
        }
    }
}

// ---------------- causal flash attention v8: barrier-free, per-wave-private -----
// 4 waves x 16 q-rows/block, 1024 blocks big-first, 3 blocks/CU. Each wave owns
// a private 3-deep K ring (gload_lds, hard-async) + private P scratch; V read as
// pre-packed fragments (VP16), register-double-buffered. NO barriers anywhere;
// counted per-wave vmcnt with FIFO ledger: entry vmcnt(8) (K issued 2 tiles ago),
// post-softmax vmcnt(4) (V issued 1 tile ago) -> zero steady-state stalls.
__global__ __launch_bounds__(256, 3)
void k_attn8(const unsigned short* __restrict__ Q,
             const unsigned short* __restrict__ K,
             const unsigned short* __restrict__ VP,
             unsigned short* __restrict__ O) {
    __shared__ unsigned short K_lds[4][3][2048];   // [wave][ring][32k x 64d]
    __shared__ unsigned short P_lds[4][16][36];    // wave-private [q][k32+pad]
    int tid = threadIdx.x, lane = tid & 63, wid = tid >> 6;
    int l15 = lane & 15, lg = lane >> 4;
    int orig = blockIdx.y * 32 + blockIdx.x;       // 1024 wgs
    int xcd = orig & 7, idx = orig >> 3;           // 128 per XCD
    int bh = xcd * 4 + (idx & 3);                  // 4 bh per XCD (L2 locality)
    int qt = 31 - ((idx >> 2) & 31);               // big tiles dispatched first
    int b = bh >> 4, h = bh & 15;
    const size_t base_qk = (size_t)b * S_LEN * E_DIM + (size_t)h * HD;
    const unsigned short* VPb = VP + (size_t)bh * 131072;
    unsigned short* Kw = &K_lds[wid][0][0];

    int qbase = qt * 64 + wid * 16;
    int q_glob = qbase + l15;
    int nkt = ((qbase + 15) >> 5) + 1;             // 32-row KV tiles, per-wave

    const unsigned short* Qb = Q + base_qk + (size_t)qbase * E_DIM;
    short8 bq[2];
#pragma unroll
    for (int s2 = 0; s2 < 2; s2++)
        bq[s2] = *(const short8*)(Qb + (size_t)l15 * E_DIM + s2 * 32 + lg * 8);

    auto stageK = [&](int ring, int kt) {          // 4 x gload16 (wave-uniform dst)
        const unsigned short* Kb = K + base_qk + (size_t)(kt * 32) * E_DIM;
#pragma unroll
        for (int i = 0; i < 4; i++) {
            int r = i * 8 + (lane >> 3);
            int cs = (lane & 7) ^ (r & 7);
            gload16(Kb + (size_t)r * E_DIM + cs * 8, Kw + ring * 2048 + i * 512);
        }
    };
    auto loadV = [&](int kt, short8 (&vv)[4]) {    // 4 coalesced 1KB frag loads
        const unsigned short* vb = VPb + (size_t)kt * 2048;
#pragma unroll
        for (int nf = 0; nf < 4; nf++)
            vv[nf] = *(const short8*)(vb + (nf * 64 + lane) * 8);
    };

    f32x4 acc_o[4] = {};
    float m_i = -1e30f, l_i = 0.f;
    short8 vA[4], vB[4];

    auto body = [&](int kt, short8 (&vCur)[4], short8 (&vNxt)[4]) {
        if (kt + 1 < nkt)
            asm volatile("s_waitcnt vmcnt(8)" ::: "memory");   // K(kt) retired
        else
            asm volatile("s_waitcnt vmcnt(4)" ::: "memory");
        const unsigned short* Kb = Kw + (kt % 3) * 2048;
        f32x4 acc_s[2] = {};
        __builtin_amdgcn_s_setprio(1);
#pragma unroll
        for (int mf = 0; mf < 2; mf++) {
            int rK = mf * 16 + l15;
#pragma unroll
            for (int s2 = 0; s2 < 2; s2++) {
                int gc = s2 * 4 + lg;
                short8 a = *(const short8*)&Kb[rK * 64 + ((gc ^ (rK & 7)) << 3)];
                acc_s[mf] = __builtin_amdgcn_mfma_f32_16x16x32_bf16(
                    a, bq[s2], acc_s[mf], 0, 0, 0);
            }
        }
        __builtin_amdgcn_s_setprio(0);
        // softmax over 8 lane-local scores (q = l15)
        float sv[8];
        float vmax = -1e30f;
        bool domask = (kt + 2 >= nkt);
#pragma unroll
        for (int mf = 0; mf < 2; mf++)
#pragma unroll
            for (int r = 0; r < 4; r++) {
                float v = acc_s[mf][r];
                if (domask) {
                    int kg = kt * 32 + mf * 16 + lg * 4 + r;
                    if (kg > q_glob) v = -1e30f;
                }
                sv[mf * 4 + r] = v;
                vmax = fmaxf(vmax, v);
            }
        vmax = fmaxf(vmax, __shfl_xor(vmax, 16));
        vmax = fmaxf(vmax, __shfl_xor(vmax, 32));
        float m_new = fmaxf(m_i, vmax);
        float corr = exp2_fast(m_i - m_new);
        float rowsum = 0.f;
#pragma unroll
        for (int i = 0; i < 8; i++) {
            float p = exp2_fast(sv[i] - m_new);
            sv[i] = p;
            rowsum += p;
        }
        rowsum += __shfl_xor(rowsum, 16);
        rowsum += __shfl_xor(rowsum, 32);
        l_i = l_i * corr + rowsum;
        m_i = m_new;
        // P -> wave-private LDS [q][k]
#pragma unroll
        for (int mf = 0; mf < 2; mf++) {
            unsigned int w0, w1;
            asm("v_cvt_pk_bf16_f32 %0, %1, %2"
                : "=v"(w0) : "v"(sv[mf * 4 + 0]), "v"(sv[mf * 4 + 1]));
            asm("v_cvt_pk_bf16_f32 %0, %1, %2"
                : "=v"(w1) : "v"(sv[mf * 4 + 2]), "v"(sv[mf * 4 + 3]));
            uint2_t w; w[0] = w0; w[1] = w1;
            *(uint2_t*)&P_lds[wid][l15][mf * 16 + lg * 4] = w;
        }
        // rescale O (rows at lg*4+r; corr lives at lane q=l15)
#pragma unroll
        for (int r = 0; r < 4; r++) {
            float c4 = __shfl(corr, lg * 4 + r);
#pragma unroll
            for (int nf = 0; nf < 4; nf++) acc_o[nf][r] *= c4;
        }
        if (kt + 1 < nkt)
            asm volatile("s_waitcnt vmcnt(4)" ::: "memory");   // V(kt) retired
        else
            asm volatile("s_waitcnt vmcnt(0)" ::: "memory");
        // PV
        short8 pa = *(const short8*)&P_lds[wid][l15][lg * 8];
        __builtin_amdgcn_s_setprio(1);
#pragma unroll
        for (int nf = 0; nf < 4; nf++)
            acc_o[nf] = __builtin_amdgcn_mfma_f32_16x16x32_bf16(
                pa, vCur[nf], acc_o[nf], 0, 0, 0);
        __builtin_amdgcn_s_setprio(0);
        // issue next: V(kt+1) then K(kt+2)  (keeps FIFO pattern K < V < K)
        if (kt + 1 < nkt) loadV(kt + 1, vNxt);
        if (kt + 2 < nkt) stageK((kt + 2) % 3, kt + 2);
    };

    // prologue: FIFO K0 < V0 < K1
    stageK(0, 0);
    loadV(0, vA);
    if (nkt > 1) stageK(1, 1);
    int kt = 0;
    while (kt < nkt) {
        body(kt, vA, vB); kt++;
        if (kt < nkt) { body(kt, vB, vA); kt++; }
    }

    // epilogue (wave-private, no barrier)
    unsigned short* Ob = O + base_qk + (size_t)qbase * E_DIM;
#pragma unroll
    for (int r = 0; r < 4; r++) {
        float linv = 1.f / __shfl(l_i, lg * 4 + r);
#pragma unroll
        for (int nf = 0; nf < 4; nf++)
            Ob[(size_t)(lg * 4 + r) * E_DIM + nf * 16 + l15] =
                f2bf(acc_o[nf][r] * linv);
    }
}

extern "C" void kernel_launch(void* const* d_in, const int* in_sizes, int n_in,
                              void* d_out, int out_size, void* d_ws, size_t ws_size,
                              hipStream_t stream) {
    (void)in_sizes; (void)n_in; (void)out_size; (void)ws_size;
    const float* x  = (const float*)d_in[0];
    const float* Wq = (const float*)d_in[1];
    const float* Wk = (const float*)d_in[2];
    const float* Wv = (const float*)d_in[3];
    const float* Wo = (const float*)d_in[4];

    unsigned short* us = (unsigned short*)d_ws;
    unsigned short* xb    = us;                  // 4096x1024
    unsigned short* WqkvT = us + 4194304;        // 3072x1024 (Wq;Wk;Wv rows)
    unsigned short* WoT   = us + 7340032;        // 1024x1024
    unsigned short* Qb    = us + 8388608;        // 4096x1024 (roped, *scale*log2e)
    unsigned short* Kb    = us + 12582912;       // 4096x1024 (roped, row-major)
    unsigned short* VP    = us + 16777216;       // VP16 frag-packed V (4.2M elems)
    unsigned short* AO    = us + 20971520;
    float* cosT = (float*)((char*)d_ws + 50331648);
    float* sinT = cosT + 65536;

    k_prep<<<6400, 256, 0, stream>>>(x, xb, Wq, Wk, Wv, Wo, WqkvT, WoT, cosT, sinT);
    k_gemm97<<<dim3(24, 32), 256, 0, stream>>>(xb, WqkvT, Qb, Kb, VP, cosT, sinT);
    k_attn8<<<dim3(32, 32), 256, 0, stream>>>(Qb, Kb, VP, AO);
    k_gemmo<128, 64, 16><<<dim3(16, 32), 256, 0, stream>>>(AO, WoT, (float*)d_out);
}

// Round 17
// 114.538 us; speedup vs baseline: 1.0366x; 1.0366x over previous
//
#include <hip/hip_runtime.h>
#include <hip/hip_bf16.h>

#define S_LEN 2048
#define E_DIM 1024
#define NH 16
#define HD 64
#define ATTN_SCALE 0.03125f                 // 1/sqrt(1024)
#define QSCALE_L2E 0.045084312f             // ATTN_SCALE * log2(e): exp2-domain softmax

typedef __attribute__((ext_vector_type(8))) short short8;
typedef __attribute__((ext_vector_type(8))) unsigned short ushort8;
typedef __attribute__((ext_vector_type(4))) unsigned short ushort4_t;
typedef __attribute__((ext_vector_type(4))) float f32x4;
typedef __attribute__((ext_vector_type(16))) float f32x16;
typedef __attribute__((ext_vector_type(4))) float f4;
typedef __attribute__((ext_vector_type(4))) unsigned int uint4v;

__device__ __forceinline__ float bf2f(unsigned short u) {
    unsigned int x = ((unsigned int)u) << 16;
    return __builtin_bit_cast(float, x);
}
__device__ __forceinline__ unsigned short f2bf(float f) {
    unsigned int x = __builtin_bit_cast(unsigned int, f);
    x += 0x7FFFu + ((x >> 16) & 1u);   // RNE
    return (unsigned short)(x >> 16);
}
__device__ __forceinline__ float exp2_fast(float x) {   // 2^x, one v_exp_f32
    float r;
    asm("v_exp_f32 %0, %1" : "=v"(r) : "v"(x));
    return r;
}
__device__ __forceinline__ void gload16(const unsigned short* g, unsigned short* l) {
    __builtin_amdgcn_global_load_lds(
        (__attribute__((address_space(1))) void*)g,
        (__attribute__((address_space(3))) void*)l, 16, 0, 0);
}

// ---------------- merged prep: x->bf16 | rope table | W transpose ----------------
__global__ __launch_bounds__(256) void k_prep(const float* __restrict__ x,
                                              unsigned short* __restrict__ xb,
                                              const float* W0, const float* W1,
                                              const float* W2, const float* W3,
                                              unsigned short* Tqkv,
                                              unsigned short* Twout,
                                              float* __restrict__ cosT,
                                              float* __restrict__ sinT) {
    int bid = blockIdx.x;
    int tid = threadIdx.x;
    if (bid < 2048) {
        size_t i = ((size_t)bid * 256 + tid) * 8;
        f4 a = *(const f4*)(x + i);
        f4 b = *(const f4*)(x + i + 4);
        ushort8 o;
        o[0] = f2bf(a[0]); o[1] = f2bf(a[1]); o[2] = f2bf(a[2]); o[3] = f2bf(a[3]);
        o[4] = f2bf(b[0]); o[5] = f2bf(b[1]); o[6] = f2bf(b[2]); o[7] = f2bf(b[3]);
        *(ushort8*)(xb + i) = o;
    } else if (bid < 2304) {
        int idx = (bid - 2048) * 256 + tid;
        int s = idx >> 5, j = idx & 31;
        float inv = expf(-(float)j * (9.210340371976184f / 32.f));
        float ang = (float)s * inv;
        cosT[idx] = cosf(ang);
        sinT[idx] = sinf(ang);
    } else {
        int t = bid - 2304;                  // 0..4095
        int bx = (t & 31) * 32, by = ((t >> 5) & 31) * 32, z = t >> 10;
        const float* W; unsigned short* T;
        switch (z) {
            case 0: W = W0; T = Tqkv; break;
            case 1: W = W1; T = Tqkv + 1048576; break;
            case 2: W = W2; T = Tqkv + 2097152; break;
            default: W = W3; T = Twout; break;
        }
        __shared__ float tile[32][33];
        int tx = tid & 31, ty = tid >> 5;    // 32 x 8
#pragma unroll
        for (int i = 0; i < 4; i++)
            tile[ty + i * 8][tx] = W[(size_t)(by + ty + i * 8) * E_DIM + bx + tx];
        __syncthreads();
#pragma unroll
        for (int i = 0; i < 4; i++)
            T[(size_t)(bx + ty + i * 8) * E_DIM + by + tx] = f2bf(tile[tx][ty + i * 8]);
    }
}

// ---------------- QKV GEMM, m97 structure (R15): RoPE Q/K + Vt[bh][d][s] --------
__global__ __launch_bounds__(256, 3)
void k_gemm97(const unsigned short* __restrict__ A,
              const unsigned short* __restrict__ B,
              unsigned short* __restrict__ Qo,
              unsigned short* __restrict__ Ko,
              unsigned short* __restrict__ Vto,
              const float* __restrict__ cosT,
              const float* __restrict__ sinT) {
    constexpr int NBN = 24;
    constexpr int NWG = 32 * NBN;            // 768
    __shared__ unsigned short Alds[4096];    // [128][32] linear
    __shared__ unsigned short Blds[4096];
    int tid = threadIdx.x, lane = tid & 63, wid = tid >> 6;
    int l15 = lane & 15, lg = lane >> 4;
    int wr = wid >> 1, wc = wid & 1;
    int orig = blockIdx.y * NBN + blockIdx.x;
    int wg = (orig & 7) * (NWG / 8) + (orig >> 3);
    int bm = wg / NBN, bn = wg % NBN;
    int c0 = wid * 2, c1c = wid * 2 + 1;
    int srow0 = c0 * 16 + (lane >> 2);
    int srow1 = c1c * 16 + (lane >> 2);
    int scol = (lane & 3) * 8;
    const unsigned short* As0 = A + (size_t)(bm * 128 + srow0) * E_DIM + scol;
    const unsigned short* As1 = A + (size_t)(bm * 128 + srow1) * E_DIM + scol;
    const unsigned short* Bs0 = B + (size_t)(bn * 128 + srow0) * E_DIM + scol;
    const unsigned short* Bs1 = B + (size_t)(bn * 128 + srow1) * E_DIM + scol;
    unsigned short* Ad0 = Alds + c0 * 512;
    unsigned short* Ad1 = Alds + c1c * 512;
    unsigned short* Bd0 = Blds + c0 * 512;
    unsigned short* Bd1 = Blds + c1c * 512;
    f32x4 acc[4][4] = {};
    for (int k0 = 0; k0 < E_DIM; k0 += 32) {
        gload16(As0 + k0, Ad0);
        gload16(As1 + k0, Ad1);
        gload16(Bs0 + k0, Bd0);
        gload16(Bs1 + k0, Bd1);
        __syncthreads();
        short8 af[4], bfr[4];
#pragma unroll
        for (int mf = 0; mf < 4; mf++)
            af[mf] = *(const short8*)(Alds + (wr * 64 + mf * 16 + l15) * 32 + lg * 8);
#pragma unroll
        for (int nf = 0; nf < 4; nf++)
            bfr[nf] = *(const short8*)(Blds + (wc * 64 + nf * 16 + l15) * 32 + lg * 8);
#pragma unroll
        for (int mf = 0; mf < 4; mf++)
#pragma unroll
            for (int nf = 0; nf < 4; nf++)
                acc[mf][nf] = __builtin_amdgcn_mfma_f32_16x16x32_bf16(
                    af[mf], bfr[nf], acc[mf][nf], 0, 0, 0);
        __syncthreads();
    }
#pragma unroll
    for (int mf = 0; mf < 4; mf++) {
        int r0 = bm * 128 + wr * 64 + mf * 16 + lg * 4;
#pragma unroll
        for (int nf = 0; nf < 4; nf++) {
            int colg = bn * 128 + wc * 64 + nf * 16 + l15;
            int z = colg >> 10, c1 = colg & 1023;
            if (z == 2) {
                int h = c1 >> 6, d = c1 & 63;
                int bb = r0 >> 11, s = r0 & 2047;
                ushort4_t p;
#pragma unroll
                for (int r = 0; r < 4; r++) p[r] = f2bf(acc[mf][nf][r]);
                *(ushort4_t*)(Vto + (((size_t)((bb * 16 + h) * 64 + d)) << 11) + s) = p;
            } else {
                unsigned short* T = z ? Ko : Qo;
                int dl = c1 & 63, j = dl >> 1;
                float sgn = (dl & 1) ? 1.f : -1.f;
                float scq = z ? 1.f : QSCALE_L2E;
#pragma unroll
                for (int r = 0; r < 4; r++) {
                    int row = r0 + r, s = row & 2047;
                    float c = cosT[s * 32 + j], sn = sinT[s * 32 + j];
                    float v = acc[mf][nf][r];
                    float p = __shfl_xor(v, 1);
                    T[(size_t)row * E_DIM + c1] = f2bf((v * c + sgn * p * sn) * scq);
                }
            }
        }
    }
}

// ---------------- out-proj GEMM (unchanged) ----------------
template <int BM, int BN, int NBN>
__global__ __launch_bounds__(256, 3)
void k_gemmo(const unsigned short* __restrict__ A,
             const unsigned short* __restrict__ B,
             float* __restrict__ Fo) {
    constexpr int THREADS = 256;
    constexpr int WM = BM / 2, WN = BN / 2;
    constexpr int FM = WM / 16, FN = WN / 16;
    constexpr int NT = E_DIM / 64;
    constexpr int AR = BM * 8 / THREADS;
    constexpr int BR = BN * 8 / THREADS;
    constexpr int STG = AR + BR;
    constexpr int NWG = (4096 / BM) * NBN;
    __shared__ unsigned short Al[2][BM * 64];
    __shared__ unsigned short Bl[2][BN * 64];
    int tid = threadIdx.x, lane = tid & 63, wid = tid >> 6;
    int l15 = lane & 15, lg = lane >> 4;
    int wr = wid >> 1, wc = wid & 1;
    int orig = blockIdx.y * NBN + blockIdx.x;
    int wg = (orig & 7) * (NWG / 8) + (orig >> 3);
    int bm = wg / NBN, bn = wg % NBN;

    auto stage = [&](int buf, int k0) {
#pragma unroll
        for (int i = 0; i < AR; i++) {
            int r = i * (THREADS / 8) + wid * 8 + (lane >> 3);
            int cs = (lane & 7) ^ (r & 7);
            gload16(A + (size_t)(bm * BM + r) * E_DIM + k0 + cs * 8,
                    &Al[buf][i * (THREADS * 8) + wid * 512]);
        }
#pragma unroll
        for (int i = 0; i < BR; i++) {
            int r = i * (THREADS / 8) + wid * 8 + (lane >> 3);
            int cs = (lane & 7) ^ (r & 7);
            gload16(B + (size_t)(bn * BN + r) * E_DIM + k0 + cs * 8,
                    &Bl[buf][i * (THREADS * 8) + wid * 512]);
        }
    };

    f32x4 acc[FM][FN] = {};
    stage(0, 0);
    for (int t = 0; t < NT; t++) {
        int cur = t & 1;
        if (t + 1 < NT) {
            stage(cur ^ 1, (t + 1) * 64);
            asm volatile("s_waitcnt vmcnt(%0)" :: "n"(STG) : "memory");
        } else {
            asm volatile("s_waitcnt vmcnt(0)" ::: "memory");
        }
        __builtin_amdgcn_s_barrier();
        __builtin_amdgcn_sched_barrier(0);
#pragma unroll
        for (int ks = 0; ks < 2; ks++) {
            short8 af[FM], bfv[FN];
#pragma unroll
            for (int m = 0; m < FM; m++) {
                int r = wr * WM + m * 16 + l15;
                int gc = ks * 4 + lg;
                af[m] = *(const short8*)&Al[cur][r * 64 + ((gc ^ (r & 7)) << 3)];
            }
#pragma unroll
            for (int n = 0; n < FN; n++) {
                int r = wc * WN + n * 16 + l15;
                int gc = ks * 4 + lg;
                bfv[n] = *(const short8*)&Bl[cur][r * 64 + ((gc ^ (r & 7)) << 3)];
            }
            __builtin_amdgcn_s_setprio(1);
#pragma unroll
            for (int m = 0; m < FM; m++)
#pragma unroll
                for (int n = 0; n < FN; n++)
                    acc[m][n] = __builtin_amdgcn_mfma_f32_16x16x32_bf16(
                        af[m], bfv[n], acc[m][n], 0, 0, 0);
            __builtin_amdgcn_s_setprio(0);
        }
        __builtin_amdgcn_s_barrier();
    }
#pragma unroll
    for (int m = 0; m < FM; m++) {
        int r0 = bm * BM + wr * WM + m * 16 + lg * 4;
#pragma unroll
        for (int n = 0; n < FN; n++) {
            int colg = bn * BN + wc * WN + n * 16 + l15;
#pragma unroll
            for (int r = 0; r < 4; r++)
                Fo[(size_t)(r0 + r) * E_DIM + colg] = acc[m][n][r];
        }
    }
}

// ---------------- causal flash attention v9: 32x32 in-lane + R11 schedule -------
// 4 waves x 32 q-rows = 128-row panel/block; 512 blocks, 3/CU (18KB LDS).
// Per-XCD panel order {15..8, 0..7} -> each CU's 2 blocks sum to uniform work.
// KVB=64 single-buffer K/V, R11 4-barrier counted-vmcnt schedule (2-load stages).
// Softmax fully in-lane (lane owns q-row; 1 shfl_xor); P in-register via
// cvt_pk + shfl_xor(32) redistribution (verified R12). O^T -> LDS transpose.
__global__ __launch_bounds__(256, 3)
void k_attn9(const unsigned short* __restrict__ Q,
             const unsigned short* __restrict__ K,
             const unsigned short* __restrict__ Vt,
             unsigned short* __restrict__ O) {
    __shared__ unsigned short lds[9216];     // K:[0,4096) V:[4096,8192) scr: all
    unsigned short* Klds = lds;
    unsigned short* Vlds = lds + 4096;
    int tid = threadIdx.x, lane = tid & 63, wid = tid >> 6;
    int l31 = lane & 31, hi = lane >> 5;
    int orig = blockIdx.y * 16 + blockIdx.x;       // 512 wgs
    int xcd = orig & 7, idx = orig >> 3;           // 64 per XCD
    int bh = xcd * 4 + (idx & 3);
    int j = idx >> 2;                              // 0..15
    int pt = (j < 8) ? (15 - j) : (j - 8);         // uniform per-CU pairing
    int b = bh >> 4, h = bh & 15;
    const size_t base_qk = (size_t)b * S_LEN * E_DIM + (size_t)h * HD;
    const unsigned short* Vbh = Vt + ((size_t)(bh * 64) << 11);

    int qbase = pt * 128 + wid * 32;
    int q_glob = qbase + l31;
    int nkt = 2 * pt + 2;                          // KV tiles of 64 (block-uniform)

    const unsigned short* Qb = Q + base_qk + (size_t)q_glob * E_DIM;
    short8 qf[4];
#pragma unroll
    for (int s = 0; s < 4; s++)
        qf[s] = *(const short8*)(Qb + s * 16 + hi * 8);

    auto stageK = [&](int kt) {                    // 64 rows x 64 d, 2 loads/thread
        const unsigned short* Kb = K + base_qk + (size_t)(kt * 64) * E_DIM;
#pragma unroll
        for (int i = 0; i < 2; i++) {
            int r = i * 32 + (tid >> 3);
            int cs = (tid & 7) ^ (r & 7);
            gload16(Kb + (size_t)r * E_DIM + cs * 8, Klds + i * 2048 + tid * 8);
        }
    };
    auto stageV = [&](int kt) {                    // 64 d x 64 k, 2 loads/thread
#pragma unroll
        for (int i = 0; i < 2; i++) {
            int r = i * 32 + (tid >> 3);
            int cs = (tid & 7) ^ (r & 7);
            gload16(Vbh + (size_t)r * 2048 + kt * 64 + cs * 8,
                    Vlds + i * 2048 + tid * 8);
        }
    };

    f32x16 ot0 = {}, ot1 = {};
    float m_i = -1e30f, l_i = 0.f;
    int swz = l31 & 7;

    stageK(0);
    stageV(0);
    asm volatile("s_waitcnt vmcnt(2)" ::: "memory");   // own K0 done
    __builtin_amdgcn_s_barrier();                      // all waves' K0 landed
    __builtin_amdgcn_sched_barrier(0);
    for (int kt = 0; kt < nkt; ++kt) {
        bool active = (kt * 64) <= (qbase + 31);
        f32x16 st0 = {}, st1 = {};
        if (active) {
            __builtin_amdgcn_s_setprio(1);
#pragma unroll
            for (int s = 0; s < 4; s++) {
                int c = ((s * 2 + hi) ^ swz) << 3;
                short8 ka0 = *(const short8*)&Klds[l31 * 64 + c];
                short8 ka1 = *(const short8*)&Klds[(32 + l31) * 64 + c];
                st0 = __builtin_amdgcn_mfma_f32_32x32x16_bf16(ka0, qf[s], st0, 0, 0, 0);
                st1 = __builtin_amdgcn_mfma_f32_32x32x16_bf16(ka1, qf[s], st1, 0, 0, 0);
            }
            __builtin_amdgcn_s_setprio(0);
        }
        __builtin_amdgcn_s_barrier();       // B1: K_lds free
        if (kt + 1 < nkt) stageK(kt + 1);
        unsigned int pk0[8], pk1[8];
        if (active) {
            // in-lane softmax (lane owns q = l31; k split across lane halves)
            float p0[16], p1[16];
            float vmax = -1e30f;
            bool domask = (kt * 64 + 63) > qbase;
            if (domask) {
#pragma unroll
                for (int r = 0; r < 16; r++) {
                    int kg = kt * 64 + (r & 3) + 8 * (r >> 2) + 4 * hi;
                    float v0 = (kg > q_glob) ? -1e30f : st0[r];
                    float v1 = (kg + 32 > q_glob) ? -1e30f : st1[r];
                    p0[r] = v0; p1[r] = v1;
                    vmax = fmaxf(vmax, fmaxf(v0, v1));
                }
            } else {
#pragma unroll
                for (int r = 0; r < 16; r++) {
                    p0[r] = st0[r]; p1[r] = st1[r];
                    vmax = fmaxf(vmax, fmaxf(st0[r], st1[r]));
                }
            }
            vmax = fmaxf(vmax, __shfl_xor(vmax, 32));
            float m_new = fmaxf(m_i, vmax);
            float corr = exp2_fast(m_i - m_new);
            float rs = 0.f;
#pragma unroll
            for (int r = 0; r < 16; r++) {
                p0[r] = exp2_fast(p0[r] - m_new);
                p1[r] = exp2_fast(p1[r] - m_new);
                rs += p0[r] + p1[r];
            }
            rs += __shfl_xor(rs, 32);
            l_i = l_i * corr + rs;
            m_i = m_new;
#pragma unroll
            for (int r = 0; r < 16; r++) { ot0[r] *= corr; ot1[r] *= corr; }
#pragma unroll
            for (int i = 0; i < 8; i++) {
                asm("v_cvt_pk_bf16_f32 %0, %1, %2"
                    : "=v"(pk0[i]) : "v"(p0[2 * i]), "v"(p0[2 * i + 1]));
                asm("v_cvt_pk_bf16_f32 %0, %1, %2"
                    : "=v"(pk1[i]) : "v"(p1[2 * i]), "v"(p1[2 * i + 1]));
            }
        }
        if (kt + 1 < nkt)
            asm volatile("s_waitcnt vmcnt(2)" ::: "memory");   // own V(kt) done
        else
            asm volatile("s_waitcnt vmcnt(0)" ::: "memory");
        __builtin_amdgcn_s_barrier();       // B2: all V(kt) landed
        __builtin_amdgcn_sched_barrier(0);
        if (active) {
            bool ishi = hi != 0;
            __builtin_amdgcn_s_setprio(1);
#pragma unroll
            for (int kk = 0; kk < 4; kk++) {
                const unsigned int* pkt = (kk & 2) ? pk1 : pk0;
                int off = (kk & 1) * 4;
                unsigned int a  = pkt[off + 0], b2 = pkt[off + 1];
                unsigned int c2 = pkt[off + 2], d2 = pkt[off + 3];
                unsigned int sa = __shfl_xor(a, 32),  sb = __shfl_xor(b2, 32);
                unsigned int sc = __shfl_xor(c2, 32), sd = __shfl_xor(d2, 32);
                uint4v w;
                w[0] = ishi ? sc : a;  w[1] = ishi ? sd : b2;
                w[2] = ishi ? c2 : sa; w[3] = ishi ? d2 : sb;
                short8 pf = __builtin_bit_cast(short8, w);
                int cv = ((kk * 2 + hi) ^ swz) << 3;
                short8 va0 = *(const short8*)&Vlds[l31 * 64 + cv];
                short8 va1 = *(const short8*)&Vlds[(32 + l31) * 64 + cv];
                ot0 = __builtin_amdgcn_mfma_f32_32x32x16_bf16(va0, pf, ot0, 0, 0, 0);
                ot1 = __builtin_amdgcn_mfma_f32_32x32x16_bf16(va1, pf, ot1, 0, 0, 0);
            }
            __builtin_amdgcn_s_setprio(0);
        }
        __builtin_amdgcn_s_barrier();       // B3: V_lds free
        if (kt + 1 < nkt) {
            stageV(kt + 1);
            asm volatile("s_waitcnt vmcnt(2)" ::: "memory");   // own K(kt+1) done
        }
        __builtin_amdgcn_s_barrier();       // B4: all K(kt+1) landed
        __builtin_amdgcn_sched_barrier(0);
    }
    // epilogue: divide (in-lane), O^T -> LDS transpose -> coalesced b128 stores
    __builtin_amdgcn_s_barrier();           // all waves done with K/V LDS
    float linv = 1.f / l_i;
    unsigned short* scb = lds + wid * 2304;     // 32 rows x 72 (pad)
#pragma unroll
    for (int i = 0; i < 8; i++) {
        int d = 2 * (i & 1) + 8 * (i >> 1) + 4 * hi;
        unsigned int w0, w1;
        float a0 = ot0[2 * i] * linv, a1 = ot0[2 * i + 1] * linv;
        float b0 = ot1[2 * i] * linv, b1 = ot1[2 * i + 1] * linv;
        asm("v_cvt_pk_bf16_f32 %0, %1, %2" : "=v"(w0) : "v"(a0), "v"(a1));
        asm("v_cvt_pk_bf16_f32 %0, %1, %2" : "=v"(w1) : "v"(b0), "v"(b1));
        *(unsigned int*)&scb[l31 * 72 + d] = w0;
        *(unsigned int*)&scb[l31 * 72 + 32 + d] = w1;
    }
    asm volatile("s_waitcnt lgkmcnt(0)" ::: "memory");
    __builtin_amdgcn_sched_barrier(0);
    int qr = lane >> 1, half = (lane & 1) * 32;
    unsigned short* Ob = O + base_qk + (size_t)(qbase + qr) * E_DIM;
#pragma unroll
    for (int jj = 0; jj < 4; jj++) {
        short8 vv = *(const short8*)&scb[qr * 72 + half + jj * 8];
        *(short8*)(Ob + half + jj * 8) = vv;
    }
}

extern "C" void kernel_launch(void* const* d_in, const int* in_sizes, int n_in,
                              void* d_out, int out_size, void* d_ws, size_t ws_size,
                              hipStream_t stream) {
    (void)in_sizes; (void)n_in; (void)out_size; (void)ws_size;
    const float* x  = (const float*)d_in[0];
    const float* Wq = (const float*)d_in[1];
    const float* Wk = (const float*)d_in[2];
    const float* Wv = (const float*)d_in[3];
    const float* Wo = (const float*)d_in[4];

    unsigned short* us = (unsigned short*)d_ws;
    unsigned short* xb    = us;                  // 4096x1024
    unsigned short* WqkvT = us + 4194304;        // 3072x1024 (Wq;Wk;Wv rows)
    unsigned short* WoT   = us + 7340032;        // 1024x1024
    unsigned short* Qb    = us + 8388608;        // 4096x1024 (roped, *scale*log2e)
    unsigned short* Kb    = us + 12582912;       // 4096x1024 (roped)
    unsigned short* Vt    = us + 16777216;       // [b][h][d][s] = [2][16][64][2048]
    unsigned short* AO    = us + 20971520;
    float* cosT = (float*)((char*)d_ws + 50331648);
    float* sinT = cosT + 65536;

    k_prep<<<6400, 256, 0, stream>>>(x, xb, Wq, Wk, Wv, Wo, WqkvT, WoT, cosT, sinT);
    k_gemm97<<<dim3(24, 32), 256, 0, stream>>>(xb, WqkvT, Qb, Kb, Vt, cosT, sinT);
    k_attn9<<<dim3(16, 32), 256, 0, stream>>>(Qb, Kb, Vt, AO);
    k_gemmo<128, 64, 16><<<dim3(16, 32), 256, 0, stream>>>(AO, WoT, (float*)d_out);
}

// Round 18
// 95.746 us; speedup vs baseline: 1.2401x; 1.1963x over previous
//
#include <hip/hip_runtime.h>
#include <hip/hip_bf16.h>

#define S_LEN 2048
#define E_DIM 1024
#define NH 16
#define HD 64
#define ATTN_SCALE 0.03125f                 // 1/sqrt(1024)
#define QSCALE_L2E 0.045084312f             // ATTN_SCALE * log2(e): exp2-domain softmax
#define KVB 128

typedef __attribute__((ext_vector_type(8))) short short8;
typedef __attribute__((ext_vector_type(8))) unsigned short ushort8;
typedef __attribute__((ext_vector_type(4))) unsigned short ushort4_t;
typedef __attribute__((ext_vector_type(4))) float f32x4;
typedef __attribute__((ext_vector_type(4))) float f4;
typedef __attribute__((ext_vector_type(2))) unsigned int uint2_t;

__device__ __forceinline__ float bf2f(unsigned short u) {
    unsigned int x = ((unsigned int)u) << 16;
    return __builtin_bit_cast(float, x);
}
__device__ __forceinline__ unsigned short f2bf(float f) {
    unsigned int x = __builtin_bit_cast(unsigned int, f);
    x += 0x7FFFu + ((x >> 16) & 1u);   // RNE
    return (unsigned short)(x >> 16);
}
__device__ __forceinline__ float exp2_fast(float x) {   // 2^x, one v_exp_f32
    float r;
    asm("v_exp_f32 %0, %1" : "=v"(r) : "v"(x));
    return r;
}
__device__ __forceinline__ void gload16(const unsigned short* g, unsigned short* l) {
    __builtin_amdgcn_global_load_lds(
        (__attribute__((address_space(1))) void*)g,
        (__attribute__((address_space(3))) void*)l, 16, 0, 0);
}

// ---------------- merged prep: x->bf16 | rope table | W transpose ----------------
__global__ __launch_bounds__(256) void k_prep(const float* __restrict__ x,
                                              unsigned short* __restrict__ xb,
                                              const float* W0, const float* W1,
                                              const float* W2, const float* W3,
                                              unsigned short* Tqkv,
                                              unsigned short* Twout,
                                              float* __restrict__ cosT,
                                              float* __restrict__ sinT) {
    int bid = blockIdx.x;
    int tid = threadIdx.x;
    if (bid < 2048) {
        size_t i = ((size_t)bid * 256 + tid) * 8;
        f4 a = *(const f4*)(x + i);
        f4 b = *(const f4*)(x + i + 4);
        ushort8 o;
        o[0] = f2bf(a[0]); o[1] = f2bf(a[1]); o[2] = f2bf(a[2]); o[3] = f2bf(a[3]);
        o[4] = f2bf(b[0]); o[5] = f2bf(b[1]); o[6] = f2bf(b[2]); o[7] = f2bf(b[3]);
        *(ushort8*)(xb + i) = o;
    } else if (bid < 2304) {
        int idx = (bid - 2048) * 256 + tid;
        int s = idx >> 5, j = idx & 31;
        float inv = expf(-(float)j * (9.210340371976184f / 32.f));
        float ang = (float)s * inv;
        cosT[idx] = cosf(ang);
        sinT[idx] = sinf(ang);
    } else {
        int t = bid - 2304;                  // 0..4095
        int bx = (t & 31) * 32, by = ((t >> 5) & 31) * 32, z = t >> 10;
        const float* W; unsigned short* T;
        switch (z) {
            case 0: W = W0; T = Tqkv; break;
            case 1: W = W1; T = Tqkv + 1048576; break;
            case 2: W = W2; T = Tqkv + 2097152; break;
            default: W = W3; T = Twout; break;
        }
        __shared__ float tile[32][33];
        int tx = tid & 31, ty = tid >> 5;    // 32 x 8
#pragma unroll
        for (int i = 0; i < 4; i++)
            tile[ty + i * 8][tx] = W[(size_t)(by + ty + i * 8) * E_DIM + bx + tx];
        __syncthreads();
#pragma unroll
        for (int i = 0; i < 4; i++)
            T[(size_t)(bx + ty + i * 8) * E_DIM + by + tx] = f2bf(tile[tx][ty + i * 8]);
    }
}

// ---------------- QKV GEMM, m97 structure with BK=64 (half the barriers) --------
// A [4096][1024] bf16, B = [Wq;Wk;Wv] [3072][1024] bf16 (pre-transposed).
// 4 waves (2x2), 4x4 frags/wave, 32 MFMA per wave per K-step, 16 K-steps.
// Linear LDS [128][64]; write chunk c of row r holds global chunk c^(r&7);
// read applies the same XOR. 32KB LDS -> 3 blocks/CU.
// Epilogue: fused RoPE (Q scaled by ATTN_SCALE*log2e), V -> Vt[bh][d][s].
__global__ __launch_bounds__(256, 3)
void k_gemm97(const unsigned short* __restrict__ A,
              const unsigned short* __restrict__ B,
              unsigned short* __restrict__ Qo,
              unsigned short* __restrict__ Ko,
              unsigned short* __restrict__ Vto,
              const float* __restrict__ cosT,
              const float* __restrict__ sinT) {
    constexpr int NBN = 24;
    constexpr int NWG = 32 * NBN;            // 768
    __shared__ unsigned short Alds[128 * 64];
    __shared__ unsigned short Blds[128 * 64];
    int tid = threadIdx.x, lane = tid & 63, wid = tid >> 6;
    int l15 = lane & 15, lg = lane >> 4;
    int wr = wid >> 1, wc = wid & 1;
    int orig = blockIdx.y * NBN + blockIdx.x;
    int wg = (orig & 7) * (NWG / 8) + (orig >> 3);   // bijective XCD swizzle
    int bm = wg / NBN, bn = wg % NBN;

    f32x4 acc[4][4] = {};
    for (int k0 = 0; k0 < E_DIM; k0 += 64) {
#pragma unroll
        for (int i = 0; i < 4; i++) {        // A: 4 x 1KB segments per wave
            int r = wid * 32 + i * 8 + (lane >> 3);
            int cs = (lane & 7) ^ (r & 7);
            gload16(A + (size_t)(bm * 128 + r) * E_DIM + k0 + cs * 8,
                    Alds + (wid * 256 + i * 64) * 8);
        }
#pragma unroll
        for (int i = 0; i < 4; i++) {        // B: 4 x 1KB segments per wave
            int r = wid * 32 + i * 8 + (lane >> 3);
            int cs = (lane & 7) ^ (r & 7);
            gload16(B + (size_t)(bn * 128 + r) * E_DIM + k0 + cs * 8,
                    Blds + (wid * 256 + i * 64) * 8);
        }
        __syncthreads();
#pragma unroll
        for (int ks = 0; ks < 2; ks++) {
            short8 af[4], bfr[4];
#pragma unroll
            for (int mf = 0; mf < 4; mf++) {
                int r = wr * 64 + mf * 16 + l15;
                int gc = ks * 4 + lg;
                af[mf] = *(const short8*)(Alds + r * 64 + ((gc ^ (r & 7)) << 3));
            }
#pragma unroll
            for (int nf = 0; nf < 4; nf++) {
                int r = wc * 64 + nf * 16 + l15;
                int gc = ks * 4 + lg;
                bfr[nf] = *(const short8*)(Blds + r * 64 + ((gc ^ (r & 7)) << 3));
            }
            __builtin_amdgcn_s_setprio(1);
#pragma unroll
            for (int mf = 0; mf < 4; mf++)
#pragma unroll
                for (int nf = 0; nf < 4; nf++)
                    acc[mf][nf] = __builtin_amdgcn_mfma_f32_16x16x32_bf16(
                        af[mf], bfr[nf], acc[mf][nf], 0, 0, 0);
            __builtin_amdgcn_s_setprio(0);
        }
        __syncthreads();
    }
    // epilogue: fused RoPE for Q/K, Vt[bh][d][s] scatter for V
#pragma unroll
    for (int mf = 0; mf < 4; mf++) {
        int r0 = bm * 128 + wr * 64 + mf * 16 + lg * 4;
#pragma unroll
        for (int nf = 0; nf < 4; nf++) {
            int colg = bn * 128 + wc * 64 + nf * 16 + l15;
            int z = colg >> 10, c1 = colg & 1023;
            if (z == 2) {
                int h = c1 >> 6, d = c1 & 63;
                int bb = r0 >> 11, s = r0 & 2047;
                ushort4_t p;
#pragma unroll
                for (int r = 0; r < 4; r++) p[r] = f2bf(acc[mf][nf][r]);
                *(ushort4_t*)(Vto + (((size_t)((bb * 16 + h) * 64 + d)) << 11) + s) = p;
            } else {
                unsigned short* T = z ? Ko : Qo;
                int dl = c1 & 63, j = dl >> 1;
                float sgn = (dl & 1) ? 1.f : -1.f;
                float scq = z ? 1.f : QSCALE_L2E;
#pragma unroll
                for (int r = 0; r < 4; r++) {
                    int row = r0 + r, s = row & 2047;
                    float c = cosT[s * 32 + j], sn = sinT[s * 32 + j];
                    float v = acc[mf][nf][r];
                    float p = __shfl_xor(v, 1);
                    T[(size_t)row * E_DIM + c1] = f2bf((v * c + sgn * p * sn) * scq);
                }
            }
        }
    }
}

// ---------------- out-proj GEMM (unchanged) ----------------
template <int BM, int BN, int NBN>
__global__ __launch_bounds__(256, 3)
void k_gemmo(const unsigned short* __restrict__ A,
             const unsigned short* __restrict__ B,
             float* __restrict__ Fo) {
    constexpr int THREADS = 256;
    constexpr int WM = BM / 2, WN = BN / 2;
    constexpr int FM = WM / 16, FN = WN / 16;
    constexpr int NT = E_DIM / 64;
    constexpr int AR = BM * 8 / THREADS;
    constexpr int BR = BN * 8 / THREADS;
    constexpr int STG = AR + BR;
    constexpr int NWG = (4096 / BM) * NBN;
    __shared__ unsigned short Al[2][BM * 64];
    __shared__ unsigned short Bl[2][BN * 64];
    int tid = threadIdx.x, lane = tid & 63, wid = tid >> 6;
    int l15 = lane & 15, lg = lane >> 4;
    int wr = wid >> 1, wc = wid & 1;
    int orig = blockIdx.y * NBN + blockIdx.x;
    int wg = (orig & 7) * (NWG / 8) + (orig >> 3);
    int bm = wg / NBN, bn = wg % NBN;

    auto stage = [&](int buf, int k0) {
#pragma unroll
        for (int i = 0; i < AR; i++) {
            int r = i * (THREADS / 8) + wid * 8 + (lane >> 3);
            int cs = (lane & 7) ^ (r & 7);
            gload16(A + (size_t)(bm * BM + r) * E_DIM + k0 + cs * 8,
                    &Al[buf][i * (THREADS * 8) + wid * 512]);
        }
#pragma unroll
        for (int i = 0; i < BR; i++) {
            int r = i * (THREADS / 8) + wid * 8 + (lane >> 3);
            int cs = (lane & 7) ^ (r & 7);
            gload16(B + (size_t)(bn * BN + r) * E_DIM + k0 + cs * 8,
                    &Bl[buf][i * (THREADS * 8) + wid * 512]);
        }
    };

    f32x4 acc[FM][FN] = {};
    stage(0, 0);
    for (int t = 0; t < NT; t++) {
        int cur = t & 1;
        if (t + 1 < NT) {
            stage(cur ^ 1, (t + 1) * 64);
            asm volatile("s_waitcnt vmcnt(%0)" :: "n"(STG) : "memory");
        } else {
            asm volatile("s_waitcnt vmcnt(0)" ::: "memory");
        }
        __builtin_amdgcn_s_barrier();
        __builtin_amdgcn_sched_barrier(0);
#pragma unroll
        for (int ks = 0; ks < 2; ks++) {
            short8 af[FM], bfv[FN];
#pragma unroll
            for (int m = 0; m < FM; m++) {
                int r = wr * WM + m * 16 + l15;
                int gc = ks * 4 + lg;
                af[m] = *(const short8*)&Al[cur][r * 64 + ((gc ^ (r & 7)) << 3)];
            }
#pragma unroll
            for (int n = 0; n < FN; n++) {
                int r = wc * WN + n * 16 + l15;
                int gc = ks * 4 + lg;
                bfv[n] = *(const short8*)&Bl[cur][r * 64 + ((gc ^ (r & 7)) << 3)];
            }
            __builtin_amdgcn_s_setprio(1);
#pragma unroll
            for (int m = 0; m < FM; m++)
#pragma unroll
                for (int n = 0; n < FN; n++)
                    acc[m][n] = __builtin_amdgcn_mfma_f32_16x16x32_bf16(
                        af[m], bfv[n], acc[m][n], 0, 0, 0);
            __builtin_amdgcn_s_setprio(0);
        }
        __builtin_amdgcn_s_barrier();
    }
#pragma unroll
    for (int m = 0; m < FM; m++) {
        int r0 = bm * BM + wr * WM + m * 16 + lg * 4;
#pragma unroll
        for (int n = 0; n < FN; n++) {
            int colg = bn * BN + wc * WN + n * 16 + l15;
#pragma unroll
            for (int r = 0; r < 4; r++)
                Fo[(size_t)(r0 + r) * E_DIM + colg] = acc[m][n][r];
        }
    }
}

// ---------------- causal flash attention: R15 body, 1024 blocks (4 waves/SIMD) --
// 4 waves x 16 q-rows = one 64-row q-tile per block; big tiles dispatched first;
// 4 bh per XCD. R11's 4-barrier counted-vmcnt schedule, KVB=128, v_exp softmax
// (exp2 domain, log2e pre-folded into Q), cvt_pk P->bf16.
__global__ __launch_bounds__(256, 3) void k_attn(const unsigned short* __restrict__ Q,
                                                 const unsigned short* __restrict__ K,
                                                 const unsigned short* __restrict__ Vt,
                                                 unsigned short* __restrict__ O) {
    __shared__ unsigned short K_lds[128 * 64];
    __shared__ unsigned short V_lds[64 * 128];
    __shared__ unsigned short P_lds[4][16][136];
    int tid = threadIdx.x, lane = tid & 63, wid = tid >> 6;
    int l15 = lane & 15, lg = lane >> 4;
    int orig = blockIdx.y * 32 + blockIdx.x;         // 1024 wgs
    int xcd = orig & 7, idx = orig >> 3;             // 128 per XCD
    int bh = xcd * 4 + (idx & 3);                    // 4 bh per XCD (L2 locality)
    int qt = 31 - ((idx >> 2) & 31);                 // big tiles first
    int b = bh >> 4, h = bh & 15;
    const size_t base_qk = (size_t)b * S_LEN * E_DIM + (size_t)h * HD;
    const unsigned short* Vbh = Vt + ((size_t)(bh * 64) << 11);

    auto stageK = [&](int kt) {
        const unsigned short* Kb = K + base_qk + (size_t)(kt * KVB) * E_DIM;
#pragma unroll
        for (int i = 0; i < 4; i++) {
            int r = i * 32 + wid * 8 + (lane >> 3);
            int cs = (lane & 7) ^ (r & 7);
            gload16(Kb + (size_t)r * E_DIM + cs * 8, K_lds + i * 2048 + wid * 512);
        }
    };
    auto stageV = [&](int kt) {
#pragma unroll
        for (int i = 0; i < 4; i++) {
            int r = i * 16 + wid * 4 + (lane >> 4);
            int cs = (lane & 15) ^ (r & 7);
            gload16(Vbh + (size_t)r * 2048 + kt * KVB + cs * 8,
                    V_lds + i * 2048 + wid * 512);
        }
    };

    const unsigned short* Qb = Q + base_qk + (size_t)(qt * 64 + wid * 16) * E_DIM;
    short8 bq[2];
#pragma unroll
    for (int s2 = 0; s2 < 2; s2++)
        bq[s2] = *(const short8*)(Qb + (size_t)l15 * E_DIM + s2 * 32 + lg * 8);
    f32x4 acc_o[4] = {};
    float m_i = -1e30f, l_i = 0.f;
    int q_glob = qt * 64 + wid * 16 + l15;
    int nkt = (qt + 2) >> 1;
    stageK(0);
    stageV(0);
    asm volatile("s_waitcnt vmcnt(4)" ::: "memory");   // own K0 done
    __builtin_amdgcn_s_barrier();                      // all waves' K0 landed
    __builtin_amdgcn_sched_barrier(0);
    for (int kt = 0; kt < nkt; ++kt) {
        // S^T = K . Q^T (exp2 domain; scale*log2e pre-folded into Q)
        f32x4 acc_s[8] = {};
        __builtin_amdgcn_s_setprio(1);
#pragma unroll
        for (int mf = 0; mf < 8; mf++) {
            int rK = mf * 16 + l15;
#pragma unroll
            for (int s2 = 0; s2 < 2; s2++) {
                int gc = s2 * 4 + lg;
                short8 a = *(const short8*)&K_lds[rK * 64 + ((gc ^ (rK & 7)) << 3)];
                acc_s[mf] = __builtin_amdgcn_mfma_f32_16x16x32_bf16(
                    a, bq[s2], acc_s[mf], 0, 0, 0);
            }
        }
        __builtin_amdgcn_s_setprio(0);
        __builtin_amdgcn_s_barrier();       // B1: K_lds free
        if (kt + 1 < nkt) stageK(kt + 1);
        float sv[32];
        float vmax = -1e30f;
        if (kt == nkt - 1) {
#pragma unroll
            for (int mf = 0; mf < 8; mf++)
#pragma unroll
                for (int r = 0; r < 4; r++) {
                    int kg = kt * KVB + mf * 16 + lg * 4 + r;
                    float v = acc_s[mf][r];
                    if (kg > q_glob) v = -1e30f;
                    sv[mf * 4 + r] = v;
                    vmax = fmaxf(vmax, v);
                }
        } else {
#pragma unroll
            for (int mf = 0; mf < 8; mf++)
#pragma unroll
                for (int r = 0; r < 4; r++) {
                    float v = acc_s[mf][r];
                    sv[mf * 4 + r] = v;
                    vmax = fmaxf(vmax, v);
                }
        }
        vmax = fmaxf(vmax, __shfl_xor(vmax, 16));
        vmax = fmaxf(vmax, __shfl_xor(vmax, 32));
        float m_new = fmaxf(m_i, vmax);
        float corr = exp2_fast(m_i - m_new);
        float rowsum = 0.f;
#pragma unroll
        for (int i = 0; i < 32; i++) {
            float p = exp2_fast(sv[i] - m_new);
            sv[i] = p;
            rowsum += p;
        }
        rowsum += __shfl_xor(rowsum, 16);
        rowsum += __shfl_xor(rowsum, 32);
        l_i = l_i * corr + rowsum;
        m_i = m_new;
        // P -> bf16 via cvt_pk, wave-private LDS [q][k]
#pragma unroll
        for (int mf = 0; mf < 8; mf++) {
            unsigned int w0, w1;
            asm("v_cvt_pk_bf16_f32 %0, %1, %2"
                : "=v"(w0) : "v"(sv[mf * 4 + 0]), "v"(sv[mf * 4 + 1]));
            asm("v_cvt_pk_bf16_f32 %0, %1, %2"
                : "=v"(w1) : "v"(sv[mf * 4 + 2]), "v"(sv[mf * 4 + 3]));
            uint2_t w; w[0] = w0; w[1] = w1;
            *(uint2_t*)&P_lds[wid][l15][mf * 16 + lg * 4] = w;
        }
        // rescale O accumulator (rows at lg*4+r; corr lives at lane q)
#pragma unroll
        for (int r = 0; r < 4; r++) {
            float c4 = __shfl(corr, lg * 4 + r);
#pragma unroll
            for (int nf = 0; nf < 4; nf++) acc_o[nf][r] *= c4;
        }
        if (kt + 1 < nkt)
            asm volatile("s_waitcnt vmcnt(4)" ::: "memory");  // own V(kt) done
        else
            asm volatile("s_waitcnt vmcnt(0)" ::: "memory");
        __builtin_amdgcn_s_barrier();       // B2: all V(kt) landed
        __builtin_amdgcn_sched_barrier(0);
        // PV: O += P . V
        __builtin_amdgcn_s_setprio(1);
#pragma unroll
        for (int s2 = 0; s2 < 4; s2++) {
            short8 pa = *(const short8*)&P_lds[wid][l15][s2 * 32 + lg * 8];
#pragma unroll
            for (int nf = 0; nf < 4; nf++) {
                int rV = nf * 16 + l15;
                int gc = s2 * 4 + lg;
                short8 bv = *(const short8*)&V_lds[rV * 128 + ((gc ^ (rV & 7)) << 3)];
                acc_o[nf] = __builtin_amdgcn_mfma_f32_16x16x32_bf16(
                    pa, bv, acc_o[nf], 0, 0, 0);
            }
        }
        __builtin_amdgcn_s_setprio(0);
        __builtin_amdgcn_s_barrier();       // B3: V_lds free
        if (kt + 1 < nkt) {
            stageV(kt + 1);
            asm volatile("s_waitcnt vmcnt(4)" ::: "memory");  // own K(kt+1) done
        }
        __builtin_amdgcn_s_barrier();       // B4: all K(kt+1) landed
        __builtin_amdgcn_sched_barrier(0);
    }
    unsigned short* Ob = O + base_qk + (size_t)(qt * 64 + wid * 16) * E_DIM;
#pragma unroll
    for (int r = 0; r < 4; r++) {
        float linv = 1.f / __shfl(l_i, lg * 4 + r);
#pragma unroll
        for (int nf = 0; nf < 4; nf++)
            Ob[(size_t)(lg * 4 + r) * E_DIM + nf * 16 + l15] =
                f2bf(acc_o[nf][r] * linv);
    }
}

extern "C" void kernel_launch(void* const* d_in, const int* in_sizes, int n_in,
                              void* d_out, int out_size, void* d_ws, size_t ws_size,
                              hipStream_t stream) {
    (void)in_sizes; (void)n_in; (void)out_size; (void)ws_size;
    const float* x  = (const float*)d_in[0];
    const float* Wq = (const float*)d_in[1];
    const float* Wk = (const float*)d_in[2];
    const float* Wv = (const float*)d_in[3];
    const float* Wo = (const float*)d_in[4];

    unsigned short* us = (unsigned short*)d_ws;
    unsigned short* xb    = us;                  // 4096x1024
    unsigned short* WqkvT = us + 4194304;        // 3072x1024 (Wq;Wk;Wv rows)
    unsigned short* WoT   = us + 7340032;        // 1024x1024
    unsigned short* Qb    = us + 8388608;        // 4096x1024 (roped, *scale*log2e)
    unsigned short* Kb    = us + 12582912;       // 4096x1024 (roped)
    unsigned short* Vt    = us + 16777216;       // [b][h][d][s] = [2][16][64][2048]
    unsigned short* AO    = us + 20971520;
    float* cosT = (float*)((char*)d_ws + 50331648);
    float* sinT = cosT + 65536;

    k_prep<<<6400, 256, 0, stream>>>(x, xb, Wq, Wk, Wv, Wo, WqkvT, WoT, cosT, sinT);
    k_gemm97<<<dim3(24, 32), 256, 0, stream>>>(xb, WqkvT, Qb, Kb, Vt, cosT, sinT);
    k_attn<<<dim3(32, 32), 256, 0, stream>>>(Qb, Kb, Vt, AO);
    k_gemmo<128, 64, 16><<<dim3(16, 32), 256, 0, stream>>>(AO, WoT, (float*)d_out);
}